// Round 1
// baseline (462.473 us; speedup 1.0000x reference)
//
#include <hip/hip_runtime.h>

typedef unsigned short u16;
typedef __attribute__((ext_vector_type(8))) short bf16x8;
typedef __attribute__((ext_vector_type(4))) float f32x4;

#define DEVI __device__ __forceinline__

// Problem dims (fixed)
static constexpr int B_ = 4, T1 = 1024, T2 = 2048, F = 1024, H = 16, DK = 64;

DEVI u16 f2bf(float f) {
    union { float f; unsigned u; } c; c.f = f;
    unsigned u = c.u + 0x7fffu + ((c.u >> 16) & 1u);   // RNE
    return (u16)(u >> 16);
}

// ---------------- cast f32 -> bf16, 4 elems/thread ----------------
__global__ __launch_bounds__(256) void cast_bf16_k(const float* __restrict__ s,
                                                   u16* __restrict__ d, int n) {
    int i = (blockIdx.x * 256 + threadIdx.x) * 4;
    if (i >= n) return;
    float4 v = *(const float4*)(s + i);
    ushort4 o;
    o.x = f2bf(v.x); o.y = f2bf(v.y); o.z = f2bf(v.z); o.w = f2bf(v.w);
    *(ushort4*)(d + i) = o;
}

// ------------- transpose + cast: W[K,N] f32 -> Wt[N,K] bf16 -------------
__global__ __launch_bounds__(256) void transpose_cast_k(const float* __restrict__ src,
                                                        u16* __restrict__ dst,
                                                        int K, int N) {
    __shared__ float tile[64][65];
    int kb = blockIdx.x * 64, nb = blockIdx.y * 64;
    int tx = threadIdx.x & 63, ty = threadIdx.x >> 6;   // 64 x 4
#pragma unroll
    for (int p = 0; p < 16; ++p) {
        int r = p * 4 + ty;
        tile[r][tx] = src[(size_t)(kb + r) * N + nb + tx];
    }
    __syncthreads();
#pragma unroll
    for (int p = 0; p < 16; ++p) {
        int r = p * 4 + ty;                              // n-offset
        dst[(size_t)(nb + r) * K + kb + tx] = f2bf(tile[tx][r]);
    }
}

// ------------- V transpose: KV[B*T2, 2F] (V half) -> Vt[B*H*DK, T2] -------------
__global__ __launch_bounds__(256) void vtrans_k(const u16* __restrict__ kv,
                                                u16* __restrict__ vt) {
    __shared__ u16 tile[64][65];
    int tb = blockIdx.x * 64;            // t2 base
    int bh = blockIdx.y;                 // b*H + h
    int b = bh / H, h = bh % H;
    int tx = threadIdx.x & 63, ty = threadIdx.x >> 6;
#pragma unroll
    for (int p = 0; p < 16; ++p) {
        int r = p * 4 + ty;              // t2 offset
        tile[r][tx] = kv[(size_t)(b * T2 + tb + r) * (2 * F) + F + h * DK + tx];
    }
    __syncthreads();
#pragma unroll
    for (int p = 0; p < 16; ++p) {
        int r = p * 4 + ty;              // d index
        vt[((size_t)bh * DK + r) * T2 + tb + tx] = tile[tx][r];
    }
}

// ------------- bf16 MFMA GEMM: C[M,N] = A[M,K] @ Bt[N,K]^T + bias -------------
// 128x128 tile, 4 waves (2x2), each wave 64x64 via 4x4 frags of 16x16x32.
// No LDS: fragments loaded straight from global (16B/lane), L1/L2 absorb reuse.
template <bool OUT_BF16>
__global__ __launch_bounds__(256) void gemm_k(const u16* __restrict__ A,
                                              const u16* __restrict__ Bt,
                                              const float* __restrict__ bias,
                                              void* __restrict__ Cout,
                                              int M, int N, int K) {
    int w = threadIdx.x >> 6, lane = threadIdx.x & 63;
    int wr = w >> 1, wc = w & 1;
    int rb = blockIdx.x * 128 + wr * 64;
    int cb = blockIdx.y * 128 + wc * 64;
    int lr = lane & 15, lg = lane >> 4;

    f32x4 acc[4][4] = {};
    const u16* Ap = A + (size_t)(rb + lr) * K + lg * 8;
    const u16* Bp = Bt + (size_t)(cb + lr) * K + lg * 8;

    for (int k0 = 0; k0 < K; k0 += 32) {
        bf16x8 a[4], b[4];
#pragma unroll
        for (int m = 0; m < 4; ++m) a[m] = *(const bf16x8*)(Ap + (size_t)m * 16 * K + k0);
#pragma unroll
        for (int n = 0; n < 4; ++n) b[n] = *(const bf16x8*)(Bp + (size_t)n * 16 * K + k0);
#pragma unroll
        for (int m = 0; m < 4; ++m)
#pragma unroll
            for (int n = 0; n < 4; ++n)
                acc[m][n] = __builtin_amdgcn_mfma_f32_16x16x32_bf16(a[m], b[n], acc[m][n], 0, 0, 0);
    }

#pragma unroll
    for (int m = 0; m < 4; ++m)
#pragma unroll
        for (int n = 0; n < 4; ++n) {
            int col = cb + n * 16 + lr;
            float bv = bias ? bias[col] : 0.f;
#pragma unroll
            for (int j = 0; j < 4; ++j) {
                int row = rb + m * 16 + lg * 4 + j;
                float v = acc[m][n][j] + bv;
                if (OUT_BF16)
                    ((u16*)Cout)[(size_t)row * N + col] = f2bf(v);
                else
                    ((float*)Cout)[(size_t)row * N + col] = v;
            }
        }
}

// ------------- fused flash-style cross attention -------------
// grid (T1/64, H, B); 4 waves, wave w owns q rows q0+16w..+15.
__global__ __launch_bounds__(256) void attn_k(const u16* __restrict__ Qb,   // [B*T1, F]
                                              const u16* __restrict__ KVb,  // [B*T2, 2F]
                                              const u16* __restrict__ Vt,   // [B*H*DK, T2]
                                              const int* __restrict__ mask, // [B, T2]
                                              u16* __restrict__ attO) {     // [B*T1, F]
    __shared__ unsigned char smask[T2];
    __shared__ u16 pbuf_all[4][16][72];   // per-wave P transpose buffer (stride 72: 16B aligned)

    int b = blockIdx.z, h = blockIdx.y, q0 = blockIdx.x * 64;
    int w = threadIdx.x >> 6, lane = threadIdx.x & 63;
    int lr = lane & 15, lg = lane >> 4;

    for (int i = threadIdx.x; i < T2; i += 256)
        smask[i] = (unsigned char)(mask[b * T2 + i] != 0);
    __syncthreads();

    const u16* qptr = Qb + (size_t)(b * T1 + q0 + w * 16 + lr) * F + h * DK + lg * 8;
    bf16x8 qf0 = *(const bf16x8*)(qptr);
    bf16x8 qf1 = *(const bf16x8*)(qptr + 32);

    float mrow[4], lsum[4];
    f32x4 oacc[4] = {};
#pragma unroll
    for (int j = 0; j < 4; ++j) { mrow[j] = -3e38f; lsum[j] = 0.f; }

    u16 (*pbuf)[72] = pbuf_all[w];
    const float scale = 0.125f;   // 1/sqrt(64)

    for (int kt = 0; kt < T2 / 64; ++kt) {
        // ---- S = Q K^T (16q x 64k per wave) ----
        f32x4 s[4] = {};
        const u16* kbase = KVb + (size_t)(b * T2 + kt * 64 + lr) * (2 * F) + h * DK + lg * 8;
#pragma unroll
        for (int ss = 0; ss < 4; ++ss) {
            bf16x8 k0 = *(const bf16x8*)(kbase + (size_t)ss * 16 * (2 * F));
            bf16x8 k1 = *(const bf16x8*)(kbase + (size_t)ss * 16 * (2 * F) + 32);
            s[ss] = __builtin_amdgcn_mfma_f32_16x16x32_bf16(qf0, k0, s[ss], 0, 0, 0);
            s[ss] = __builtin_amdgcn_mfma_f32_16x16x32_bf16(qf1, k1, s[ss], 0, 0, 0);
        }
        bool ok[4];
#pragma unroll
        for (int ss = 0; ss < 4; ++ss) ok[ss] = smask[kt * 64 + ss * 16 + lr] != 0;

        // ---- online softmax (rows live in reg j across 16-lane groups) ----
        float tm[4];
#pragma unroll
        for (int j = 0; j < 4; ++j) {
            float v = -3e38f;
#pragma unroll
            for (int ss = 0; ss < 4; ++ss) {
                float sv = ok[ss] ? s[ss][j] * scale : -3e38f;
                v = fmaxf(v, sv);
            }
#pragma unroll
            for (int off = 1; off < 16; off <<= 1) v = fmaxf(v, __shfl_xor(v, off));
            tm[j] = v;
        }
        float corr[4], pv[4][4];
#pragma unroll
        for (int j = 0; j < 4; ++j) {
            float mnew = fmaxf(mrow[j], tm[j]);
            corr[j] = __expf(mrow[j] - mnew);
            mrow[j] = mnew;
            float r = 0.f;
#pragma unroll
            for (int ss = 0; ss < 4; ++ss) {
                float p = ok[ss] ? __expf(s[ss][j] * scale - mnew) : 0.f;
                pv[ss][j] = p;
                r += p;
            }
#pragma unroll
            for (int off = 1; off < 16; off <<= 1) r += __shfl_xor(r, off);
            lsum[j] = lsum[j] * corr[j] + r;
        }
#pragma unroll
        for (int d = 0; d < 4; ++d) {
            f32x4 t = oacc[d];
#pragma unroll
            for (int j = 0; j < 4; ++j) t[j] *= corr[j];
            oacc[d] = t;
        }

        // ---- P: C-layout -> A-layout via per-wave LDS ----
#pragma unroll
        for (int ss = 0; ss < 4; ++ss)
#pragma unroll
            for (int j = 0; j < 4; ++j)
                pbuf[lg * 4 + j][ss * 16 + lr] = f2bf(pv[ss][j]);

        bf16x8 pa0 = *(const bf16x8*)(&pbuf[lr][lg * 8]);
        bf16x8 pa1 = *(const bf16x8*)(&pbuf[lr][32 + lg * 8]);

        // ---- O += P V ----
        const u16* vbase = Vt + ((size_t)(b * H + h) * DK + lr) * T2 + kt * 64 + lg * 8;
#pragma unroll
        for (int d = 0; d < 4; ++d) {
            bf16x8 v0 = *(const bf16x8*)(vbase + (size_t)d * 16 * T2);
            bf16x8 v1 = *(const bf16x8*)(vbase + (size_t)d * 16 * T2 + 32);
            oacc[d] = __builtin_amdgcn_mfma_f32_16x16x32_bf16(pa0, v0, oacc[d], 0, 0, 0);
            oacc[d] = __builtin_amdgcn_mfma_f32_16x16x32_bf16(pa1, v1, oacc[d], 0, 0, 0);
        }
    }

    // ---- epilogue: O / lsum -> attO bf16 ----
#pragma unroll
    for (int d = 0; d < 4; ++d)
#pragma unroll
        for (int j = 0; j < 4; ++j) {
            int row = q0 + w * 16 + lg * 4 + j;
            int col = h * DK + d * 16 + lr;
            float denom = lsum[j] > 0.f ? lsum[j] : 1.f;
            attO[(size_t)(b * T1 + row) * F + col] = f2bf(oacc[d][j] / denom);
        }
}

extern "C" void kernel_launch(void* const* d_in, const int* in_sizes, int n_in,
                              void* d_out, int out_size, void* d_ws, size_t ws_size,
                              hipStream_t stream) {
    const float* x      = (const float*)d_in[0];
    const float* memory = (const float*)d_in[1];
    const int*   mmask  = (const int*)d_in[2];
    const float* Wq     = (const float*)d_in[3];
    const float* bq     = (const float*)d_in[4];
    const float* Wkv    = (const float*)d_in[5];
    const float* bkv    = (const float*)d_in[6];
    const float* Wo     = (const float*)d_in[7];
    const float* bo     = (const float*)d_in[8];
    float* out = (float*)d_out;
    char* ws = (char*)d_ws;

    // workspace layout (72 MB total)
    u16* xb   = (u16*)(ws);                  // [4096,1024]  8 MB   (reused as attO)
    u16* mb   = (u16*)(ws + (8u  << 20));    // [8192,1024] 16 MB   (reused as Vt)
    u16* Wqt  = (u16*)(ws + (24u << 20));    // [1024,1024]  2 MB
    u16* Wkvt = (u16*)(ws + (26u << 20));    // [2048,1024]  4 MB
    u16* Wot  = (u16*)(ws + (30u << 20));    // [1024,1024]  2 MB
    u16* Qb   = (u16*)(ws + (32u << 20));    // [4096,1024]  8 MB
    u16* KVb  = (u16*)(ws + (40u << 20));    // [8192,2048] 32 MB
    u16* Vt   = mb;
    u16* attO = xb;

    // 1. casts
    cast_bf16_k<<<(B_ * T1 * F) / 1024, 256, 0, stream>>>(x, xb, B_ * T1 * F);
    cast_bf16_k<<<(B_ * T2 * F) / 1024, 256, 0, stream>>>(memory, mb, B_ * T2 * F);

    // 2. weight transposes
    transpose_cast_k<<<dim3(F / 64, F / 64), 256, 0, stream>>>(Wq, Wqt, F, F);
    transpose_cast_k<<<dim3(F / 64, 2 * F / 64), 256, 0, stream>>>(Wkv, Wkvt, F, 2 * F);
    transpose_cast_k<<<dim3(F / 64, F / 64), 256, 0, stream>>>(Wo, Wot, F, F);

    // 3. projections
    gemm_k<true><<<dim3(B_ * T1 / 128, F / 128), 256, 0, stream>>>(xb, Wqt, bq, Qb, B_ * T1, F, F);
    gemm_k<true><<<dim3(B_ * T2 / 128, 2 * F / 128), 256, 0, stream>>>(mb, Wkvt, bkv, KVb, B_ * T2, 2 * F, F);

    // 4. V transpose to [B*H*DK, T2]
    vtrans_k<<<dim3(T2 / 64, B_ * H), 256, 0, stream>>>(KVb, Vt);

    // 5. attention
    attn_k<<<dim3(T1 / 64, H, B_), 256, 0, stream>>>(Qb, KVb, Vt, mmask, attO);

    // 6. output projection (f32 out)
    gemm_k<false><<<dim3(B_ * T1 / 128, F / 128), 256, 0, stream>>>(attO, Wot, bo, out, B_ * T1, F, F);
}

// Round 2
// 359.558 us; speedup vs baseline: 1.2862x; 1.2862x over previous
//
#include <hip/hip_runtime.h>

typedef unsigned short u16;
typedef __attribute__((ext_vector_type(8))) short bf16x8;
typedef __attribute__((ext_vector_type(4))) float f32x4;

#define DEVI __device__ __forceinline__

// Problem dims (fixed)
static constexpr int B_ = 4, T1 = 1024, T2 = 2048, F = 1024, H = 16, DK = 64;

typedef __attribute__((address_space(3))) unsigned lds_u32;
typedef __attribute__((address_space(1))) const unsigned gmem_u32;

DEVI u16 f2bf(float f) {                       // RNE
    union { float f; unsigned u; } c; c.f = f;
    unsigned u = c.u + 0x7fffu + ((c.u >> 16) & 1u);
    return (u16)(u >> 16);
}
DEVI u16 f2bf_fast(float f) {                  // round-half-up (P values in [0,~1])
    union { float f; unsigned u; } c; c.f = f;
    return (u16)((c.u + 0x8000u) >> 16);
}

// ---------------- cast f32 -> bf16, 4 elems/thread ----------------
__global__ __launch_bounds__(256) void cast_bf16_k(const float* __restrict__ s,
                                                   u16* __restrict__ d, int n) {
    int i = (blockIdx.x * 256 + threadIdx.x) * 4;
    if (i >= n) return;
    float4 v = *(const float4*)(s + i);
    ushort4 o;
    o.x = f2bf(v.x); o.y = f2bf(v.y); o.z = f2bf(v.z); o.w = f2bf(v.w);
    *(ushort4*)(d + i) = o;
}

// ------------- transpose + cast: W[K,N] f32 -> Wt[N,K] bf16 -------------
__global__ __launch_bounds__(256) void transpose_cast_k(const float* __restrict__ src,
                                                        u16* __restrict__ dst,
                                                        int K, int N) {
    __shared__ float tile[64][65];
    int kb = blockIdx.x * 64, nb = blockIdx.y * 64;
    int tx = threadIdx.x & 63, ty = threadIdx.x >> 6;   // 64 x 4
#pragma unroll
    for (int p = 0; p < 16; ++p) {
        int r = p * 4 + ty;
        tile[r][tx] = src[(size_t)(kb + r) * N + nb + tx];
    }
    __syncthreads();
#pragma unroll
    for (int p = 0; p < 16; ++p) {
        int r = p * 4 + ty;                              // n-offset
        dst[(size_t)(nb + r) * K + kb + tx] = f2bf(tile[tx][r]);
    }
}

// ------------- V transpose: KV[B*T2, 2F] (V half) -> Vt[B*H*DK, T2] -------------
__global__ __launch_bounds__(256) void vtrans_k(const u16* __restrict__ kv,
                                                u16* __restrict__ vt) {
    __shared__ u16 tile[64][65];
    int tb = blockIdx.x * 64;            // t2 base
    int bh = blockIdx.y;                 // b*H + h
    int b = bh / H, h = bh % H;
    int tx = threadIdx.x & 63, ty = threadIdx.x >> 6;
#pragma unroll
    for (int p = 0; p < 16; ++p) {
        int r = p * 4 + ty;              // t2 offset
        tile[r][tx] = kv[(size_t)(b * T2 + tb + r) * (2 * F) + F + h * DK + tx];
    }
    __syncthreads();
#pragma unroll
    for (int p = 0; p < 16; ++p) {
        int r = p * 4 + ty;              // d index
        vt[((size_t)bh * DK + r) * T2 + tb + tx] = tile[tx][r];
    }
}

// ------------- bf16 MFMA GEMM (m97 structure): C = (A @ Bt^T + bias) * scale ----
// 128x128 tile, BK=64, 4 waves (2x2). LDS staged via global_load_lds width-16
// with pre-swizzled global source (linear LDS dest) + XOR-swizzled ds_read.
// Swizzle: logical chunk cl at linear chunk cd, cl = cd ^ (row&7); row stride
// 128B = 32 dwords so bank = f(chunk' only) -> conflict-free reads.
template <bool OUT_BF16>
__global__ __launch_bounds__(256) void gemm_k(const u16* __restrict__ A,
                                              const u16* __restrict__ Bt,
                                              const float* __restrict__ bias,
                                              float scale,
                                              void* __restrict__ Cout,
                                              int M, int N, int K) {
    __shared__ u16 ldsA[128 * 64];   // 16 KB
    __shared__ u16 ldsB[128 * 64];   // 16 KB
    const int t = threadIdx.x;
    const int w = t >> 6, lane = t & 63;
    const int wr = w >> 1, wc = w & 1;
    const int lr = lane & 15, lg = lane >> 4;

    // staging map: linear chunk c = i*256 + t ; row = c>>3 = i*32 + (t>>3);
    // dest chunk-in-row cd = t&7 ; logical chunk cl = cd ^ (row&7) (i*32 % 8 == 0)
    const int r0 = t >> 3;
    const int cl = (t & 7) ^ (r0 & 7);
    const u16* Ag = A + (size_t)(blockIdx.x * 128 + r0) * K + cl * 8;
    const u16* Bg = Bt + (size_t)(blockIdx.y * 128 + r0) * K + cl * 8;

    f32x4 acc[4][4] = {};

    for (int k0 = 0; k0 < K; k0 += 64) {
#pragma unroll
        for (int i = 0; i < 4; ++i) {
            __builtin_amdgcn_global_load_lds(
                (gmem_u32*)(Ag + (size_t)i * 32 * K + k0),
                (lds_u32*)((char*)ldsA + i * 4096 + w * 1024), 16, 0, 0);
            __builtin_amdgcn_global_load_lds(
                (gmem_u32*)(Bg + (size_t)i * 32 * K + k0),
                (lds_u32*)((char*)ldsB + i * 4096 + w * 1024), 16, 0, 0);
        }
        __syncthreads();

        bf16x8 a[2][4], b[2][4];
#pragma unroll
        for (int kk = 0; kk < 2; ++kk)
#pragma unroll
            for (int m = 0; m < 4; ++m) {
                int ra = wr * 64 + m * 16 + lr;
                int rb = wc * 64 + m * 16 + lr;
                int c = kk * 4 + lg;
                a[kk][m] = *(const bf16x8*)&ldsA[ra * 64 + ((c ^ (ra & 7)) * 8)];
                b[kk][m] = *(const bf16x8*)&ldsB[rb * 64 + ((c ^ (rb & 7)) * 8)];
            }
#pragma unroll
        for (int kk = 0; kk < 2; ++kk)
#pragma unroll
            for (int m = 0; m < 4; ++m)
#pragma unroll
                for (int n = 0; n < 4; ++n)
                    acc[m][n] = __builtin_amdgcn_mfma_f32_16x16x32_bf16(a[kk][m], b[kk][n], acc[m][n], 0, 0, 0);
        __syncthreads();
    }

    const int rbase = blockIdx.x * 128 + wr * 64;
    const int cbase = blockIdx.y * 128 + wc * 64;
#pragma unroll
    for (int m = 0; m < 4; ++m)
#pragma unroll
        for (int n = 0; n < 4; ++n) {
            int col = cbase + n * 16 + lr;
            float bv = bias ? bias[col] : 0.f;
#pragma unroll
            for (int j = 0; j < 4; ++j) {
                int row = rbase + m * 16 + lg * 4 + j;
                float v = (acc[m][n][j] + bv) * scale;
                if (OUT_BF16)
                    ((u16*)Cout)[(size_t)row * N + col] = f2bf(v);
                else
                    ((float*)Cout)[(size_t)row * N + col] = v;
            }
        }
}

// ------------- fused flash-style cross attention -------------
// grid (H, T1/64, B): same-(b,h) blocks land on the same XCD (id%8 round robin).
// 4 waves, wave w owns q rows q0+16w..+15. Q pre-scaled by 1/sqrt(dk) in Q-GEMM.
// K-tile register double-buffer prefetch; V loads issued early each tile.
// Mask is additive (-1e30); online-softmax rescale self-corrects any
// all-masked-prefix bogus contributions (corr underflows to 0).

#define LOADK(DST, KT) do {                                                        \
    const u16* kb_ = kbase0 + (size_t)(KT) * 64 * (2 * F);                         \
    _Pragma("unroll")                                                              \
    for (int ss_ = 0; ss_ < 4; ++ss_) {                                            \
        DST[2 * ss_]     = *(const bf16x8*)(kb_ + (size_t)ss_ * 16 * (2 * F));     \
        DST[2 * ss_ + 1] = *(const bf16x8*)(kb_ + (size_t)ss_ * 16 * (2 * F) + 32);\
    } } while (0)

#define ATTN_TILE(KF, KP, KT, PT, DOPRE) do {                                      \
    bf16x8 vf_[8];                                                                 \
    const u16* vb_ = vbase0 + (size_t)(KT) * 64;                                   \
    _Pragma("unroll")                                                              \
    for (int d_ = 0; d_ < 4; ++d_) {                                               \
        vf_[2 * d_]     = *(const bf16x8*)(vb_ + (size_t)d_ * 16 * T2);            \
        vf_[2 * d_ + 1] = *(const bf16x8*)(vb_ + (size_t)d_ * 16 * T2 + 32);       \
    }                                                                              \
    if (DOPRE) { LOADK(KP, PT); }                                                  \
    f32x4 s_[4] = {};                                                              \
    _Pragma("unroll")                                                              \
    for (int ss_ = 0; ss_ < 4; ++ss_) {                                            \
        s_[ss_] = __builtin_amdgcn_mfma_f32_16x16x32_bf16(qf0, KF[2 * ss_],     s_[ss_], 0, 0, 0); \
        s_[ss_] = __builtin_amdgcn_mfma_f32_16x16x32_bf16(qf1, KF[2 * ss_ + 1], s_[ss_], 0, 0, 0); \
    }                                                                              \
    float mb_[4];                                                                  \
    _Pragma("unroll")                                                              \
    for (int ss_ = 0; ss_ < 4; ++ss_) mb_[ss_] = smaskf[(KT) * 64 + ss_ * 16 + lr];\
    float corr_[4];                                                                \
    _Pragma("unroll")                                                              \
    for (int j_ = 0; j_ < 4; ++j_) {                                               \
        float v_ = s_[0][j_] + mb_[0];                                             \
        v_ = fmaxf(v_, s_[1][j_] + mb_[1]);                                        \
        v_ = fmaxf(v_, s_[2][j_] + mb_[2]);                                        \
        v_ = fmaxf(v_, s_[3][j_] + mb_[3]);                                        \
        _Pragma("unroll")                                                          \
        for (int o_ = 1; o_ < 16; o_ <<= 1) v_ = fmaxf(v_, __shfl_xor(v_, o_));    \
        float mn_ = fmaxf(mrow[j_], v_);                                           \
        corr_[j_] = __expf(mrow[j_] - mn_);                                        \
        mrow[j_] = mn_;                                                            \
        float pt_ = 0.f;                                                           \
        _Pragma("unroll")                                                          \
        for (int ss_ = 0; ss_ < 4; ++ss_) {                                        \
            float p_ = __expf(s_[ss_][j_] + mb_[ss_] - mn_);                       \
            pt_ += p_;                                                             \
            pbuf[lg * 4 + j_][ss_ * 16 + lr] = f2bf_fast(p_);                      \
        }                                                                          \
        lsum[j_] = lsum[j_] * corr_[j_] + pt_;                                     \
    }                                                                              \
    _Pragma("unroll")                                                              \
    for (int d_ = 0; d_ < 4; ++d_) {                                               \
        _Pragma("unroll")                                                          \
        for (int j_ = 0; j_ < 4; ++j_) oacc[d_][j_] *= corr_[j_];                  \
    }                                                                              \
    bf16x8 pa0_ = *(const bf16x8*)(&pbuf[lr][lg * 8]);                             \
    bf16x8 pa1_ = *(const bf16x8*)(&pbuf[lr][32 + lg * 8]);                        \
    _Pragma("unroll")                                                              \
    for (int d_ = 0; d_ < 4; ++d_) {                                               \
        oacc[d_] = __builtin_amdgcn_mfma_f32_16x16x32_bf16(pa0_, vf_[2 * d_],     oacc[d_], 0, 0, 0); \
        oacc[d_] = __builtin_amdgcn_mfma_f32_16x16x32_bf16(pa1_, vf_[2 * d_ + 1], oacc[d_], 0, 0, 0); \
    } } while (0)

__global__ __launch_bounds__(256) void attn_k(const u16* __restrict__ Qb,   // [B*T1, F] (pre-scaled)
                                              const u16* __restrict__ KVb,  // [B*T2, 2F]
                                              const u16* __restrict__ Vt,   // [B*H*DK, T2]
                                              const int* __restrict__ mask, // [B, T2]
                                              u16* __restrict__ attO) {     // [B*T1, F]
    __shared__ float smaskf[T2];          // 8 KB: 0 or -1e30
    __shared__ u16 pbuf_all[4][16][72];   // per-wave P transpose buffer

    int h = blockIdx.x, q0 = blockIdx.y * 64, b = blockIdx.z;
    int w = threadIdx.x >> 6, lane = threadIdx.x & 63;
    int lr = lane & 15, lg = lane >> 4;

    for (int i = threadIdx.x; i < T2; i += 256)
        smaskf[i] = mask[b * T2 + i] ? 0.f : -1e30f;
    __syncthreads();

    const u16* qptr = Qb + (size_t)(b * T1 + q0 + w * 16 + lr) * F + h * DK + lg * 8;
    bf16x8 qf0 = *(const bf16x8*)(qptr);
    bf16x8 qf1 = *(const bf16x8*)(qptr + 32);

    float mrow[4], lsum[4];
    f32x4 oacc[4] = {};
#pragma unroll
    for (int j = 0; j < 4; ++j) { mrow[j] = -3e38f; lsum[j] = 0.f; }

    u16 (*pbuf)[72] = pbuf_all[w];
    const u16* kbase0 = KVb + (size_t)(b * T2 + lr) * (2 * F) + h * DK + lg * 8;
    const u16* vbase0 = Vt + ((size_t)(b * H + h) * DK + lr) * T2 + lg * 8;

    bf16x8 kA[8], kB[8];
    LOADK(kA, 0);

    for (int i = 0; i < 16; ++i) {
        ATTN_TILE(kA, kB, 2 * i,     2 * i + 1, true);
        ATTN_TILE(kB, kA, 2 * i + 1, 2 * i + 2, (i < 15));
    }

    // epilogue: deferred lsum reduce, then O / lsum -> attO bf16
#pragma unroll
    for (int j = 0; j < 4; ++j) {
        float v = lsum[j];
#pragma unroll
        for (int o = 1; o < 16; o <<= 1) v += __shfl_xor(v, o);
        lsum[j] = v > 0.f ? 1.f / v : 1.f;
    }
#pragma unroll
    for (int d = 0; d < 4; ++d)
#pragma unroll
        for (int j = 0; j < 4; ++j) {
            int row = q0 + w * 16 + lg * 4 + j;
            int col = h * DK + d * 16 + lr;
            attO[(size_t)(b * T1 + row) * F + col] = f2bf(oacc[d][j] * lsum[j]);
        }
}

extern "C" void kernel_launch(void* const* d_in, const int* in_sizes, int n_in,
                              void* d_out, int out_size, void* d_ws, size_t ws_size,
                              hipStream_t stream) {
    const float* x      = (const float*)d_in[0];
    const float* memory = (const float*)d_in[1];
    const int*   mmask  = (const int*)d_in[2];
    const float* Wq     = (const float*)d_in[3];
    const float* bq     = (const float*)d_in[4];
    const float* Wkv    = (const float*)d_in[5];
    const float* bkv    = (const float*)d_in[6];
    const float* Wo     = (const float*)d_in[7];
    const float* bo     = (const float*)d_in[8];
    float* out = (float*)d_out;
    char* ws = (char*)d_ws;

    // workspace layout (72 MB total)
    u16* xb   = (u16*)(ws);                  // [4096,1024]  8 MB   (reused as attO)
    u16* mb   = (u16*)(ws + (8u  << 20));    // [8192,1024] 16 MB   (reused as Vt)
    u16* Wqt  = (u16*)(ws + (24u << 20));    // [1024,1024]  2 MB
    u16* Wkvt = (u16*)(ws + (26u << 20));    // [2048,1024]  4 MB
    u16* Wot  = (u16*)(ws + (30u << 20));    // [1024,1024]  2 MB
    u16* Qb   = (u16*)(ws + (32u << 20));    // [4096,1024]  8 MB
    u16* KVb  = (u16*)(ws + (40u << 20));    // [8192,2048] 32 MB
    u16* Vt   = mb;
    u16* attO = xb;

    // 1. casts
    cast_bf16_k<<<(B_ * T1 * F) / 1024, 256, 0, stream>>>(x, xb, B_ * T1 * F);
    cast_bf16_k<<<(B_ * T2 * F) / 1024, 256, 0, stream>>>(memory, mb, B_ * T2 * F);

    // 2. weight transposes
    transpose_cast_k<<<dim3(F / 64, F / 64), 256, 0, stream>>>(Wq, Wqt, F, F);
    transpose_cast_k<<<dim3(F / 64, 2 * F / 64), 256, 0, stream>>>(Wkv, Wkvt, F, 2 * F);
    transpose_cast_k<<<dim3(F / 64, F / 64), 256, 0, stream>>>(Wo, Wot, F, F);

    // 3. projections (Q pre-scaled by 1/sqrt(dk))
    gemm_k<true><<<dim3(B_ * T1 / 128, F / 128), 256, 0, stream>>>(xb, Wqt, bq, 0.125f, Qb, B_ * T1, F, F);
    gemm_k<true><<<dim3(B_ * T2 / 128, 2 * F / 128), 256, 0, stream>>>(mb, Wkvt, bkv, 1.f, KVb, B_ * T2, 2 * F, F);

    // 4. V transpose to [B*H*DK, T2]
    vtrans_k<<<dim3(T2 / 64, B_ * H), 256, 0, stream>>>(KVb, Vt);

    // 5. attention
    attn_k<<<dim3(H, T1 / 64, B_), 256, 0, stream>>>(Qb, KVb, Vt, mmask, attO);

    // 6. output projection (f32 out)
    gemm_k<false><<<dim3(B_ * T1 / 128, F / 128), 256, 0, stream>>>(attO, Wot, bo, 1.f, out, B_ * T1, F, F);
}